// Round 1
// baseline (886.363 us; speedup 1.0000x reference)
//
#include <hip/hip_runtime.h>
#include <hip/hip_bf16.h>
#include <math.h>

#define S_LEN 2048
#define D_DIM 128
#define KVT 64
#define QT 64
#define PADK 136   // 128 + 8 bf16 pad
#define PADV 72    // 64 + 8 bf16 pad

typedef short bf8_t __attribute__((ext_vector_type(8)));   // 8 bf16 (4 VGPR)
typedef float f32x4 __attribute__((ext_vector_type(4)));

__device__ __forceinline__ short f2bf(float f) {
    union { float f; unsigned u; } x; x.f = f;
    unsigned u = x.u;
    u += 0x7FFF + ((u >> 16) & 1);   // RNE
    return (short)(u >> 16);
}
__device__ __forceinline__ float bf2f(short h) {
    union { unsigned u; float f; } x;
    x.u = ((unsigned)(unsigned short)h) << 16;
    return x.f;
}

// LDS map (in shorts):
//  khi:  [64][136]            0     .. 8704
//  klo:  [64][136]            8704  .. 17408
//  vt :  [128][72]  (V^T)     17408 .. 26624
//  p  :  4 x [16][72]         26624 .. 31232   (per-wave scratch)
#define LDS_SHORTS 31232

__global__ __launch_bounds__(256, 2)
void attn_fwd(const float* __restrict__ Q, const float* __restrict__ K,
              const float* __restrict__ V, float* __restrict__ O)
{
    __shared__ short lds[LDS_SHORTS];
    short* khi = lds;
    short* klo = lds + 8704;
    short* vt  = lds + 17408;
    short* pls = lds + 26624;

    const int tid  = threadIdx.x;
    const int w    = tid >> 6;
    const int lane = tid & 63;
    const int lg   = lane & 15;   // row/col-in-16
    const int gq   = lane >> 4;   // 16-lane group 0..3

    const int qblk = blockIdx.x;  // 0..31
    const int bh   = blockIdx.y;  // 0..63

    const size_t base = (size_t)bh * S_LEN * D_DIM;
    const int qrow0 = qblk * QT + w * 16;

    // ---- Q fragments (hi/lo split), held in registers ----
    bf8_t qhi[4], qlo[4];
    {
        const float* qp = Q + base + (size_t)(qrow0 + lg) * D_DIM;
        #pragma unroll
        for (int c = 0; c < 4; ++c) {
            const int d0 = c * 32 + gq * 8;
            #pragma unroll
            for (int j = 0; j < 8; ++j) {
                float f = qp[d0 + j];
                short h = f2bf(f);
                qhi[c][j] = h;
                qlo[c][j] = f2bf(f - bf2f(h));
            }
        }
    }

    f32x4 oacc[8];
    #pragma unroll
    for (int n = 0; n < 8; ++n) oacc[n] = (f32x4){0.f, 0.f, 0.f, 0.f};
    float mrow[4] = {-INFINITY, -INFINITY, -INFINITY, -INFINITY};
    float lrow[4] = {0.f, 0.f, 0.f, 0.f};

    for (int kv = 0; kv < S_LEN; kv += KVT) {
        __syncthreads();   // previous iteration's LDS reads done
        // ---- stage K (hi/lo) and V^T into LDS, coalesced ----
        {
            const float4* kg = (const float4*)(K + base + (size_t)kv * D_DIM);
            const float4* vg = (const float4*)(V + base + (size_t)kv * D_DIM);
            #pragma unroll
            for (int it = 0; it < 8; ++it) {
                const int f4  = it * 256 + tid;   // 0..2047
                const int row = f4 >> 5;          // 0..63
                const int d   = (f4 & 31) * 4;
                float4 kk = kg[f4];
                float4 vv = vg[f4];
                short h0 = f2bf(kk.x), h1 = f2bf(kk.y), h2 = f2bf(kk.z), h3 = f2bf(kk.w);
                short4 hw; hw.x = h0; hw.y = h1; hw.z = h2; hw.w = h3;
                *(short4*)(&khi[row * PADK + d]) = hw;
                short4 lw;
                lw.x = f2bf(kk.x - bf2f(h0));
                lw.y = f2bf(kk.y - bf2f(h1));
                lw.z = f2bf(kk.z - bf2f(h2));
                lw.w = f2bf(kk.w - bf2f(h3));
                *(short4*)(&klo[row * PADK + d]) = lw;
                vt[(d + 0) * PADV + row] = f2bf(vv.x);
                vt[(d + 1) * PADV + row] = f2bf(vv.y);
                vt[(d + 2) * PADV + row] = f2bf(vv.z);
                vt[(d + 3) * PADV + row] = f2bf(vv.w);
            }
        }
        __syncthreads();

        // ---- S = Q K^T for this wave's 16 q-rows, 4 tiles of 16 k-cols ----
        f32x4 sacc[4];
        #pragma unroll
        for (int t = 0; t < 4; ++t) sacc[t] = (f32x4){0.f, 0.f, 0.f, 0.f};
        #pragma unroll
        for (int t = 0; t < 4; ++t) {
            const int krow = t * 16 + lg;
            #pragma unroll
            for (int c = 0; c < 4; ++c) {
                bf8_t kh = *(const bf8_t*)(&khi[krow * PADK + c * 32 + gq * 8]);
                bf8_t kl = *(const bf8_t*)(&klo[krow * PADK + c * 32 + gq * 8]);
                sacc[t] = __builtin_amdgcn_mfma_f32_16x16x32_bf16(qhi[c], kh, sacc[t], 0, 0, 0);
                sacc[t] = __builtin_amdgcn_mfma_f32_16x16x32_bf16(qlo[c], kh, sacc[t], 0, 0, 0);
                sacc[t] = __builtin_amdgcn_mfma_f32_16x16x32_bf16(qhi[c], kl, sacc[t], 0, 0, 0);
            }
        }

        // ---- online softmax (rows live in 16-lane groups) ----
        float scl[4];
        #pragma unroll
        for (int r = 0; r < 4; ++r) {
            float tm = fmaxf(fmaxf(sacc[0][r], sacc[1][r]),
                             fmaxf(sacc[2][r], sacc[3][r]));
            #pragma unroll
            for (int off = 8; off >= 1; off >>= 1)
                tm = fmaxf(tm, __shfl_xor(tm, off, 64));
            const float mn = fmaxf(mrow[r], tm);
            const float sc = __expf(mrow[r] - mn);
            float ps = 0.f;
            #pragma unroll
            for (int t = 0; t < 4; ++t) {
                float p = __expf(sacc[t][r] - mn);
                sacc[t][r] = p;
                ps += p;
            }
            #pragma unroll
            for (int off = 8; off >= 1; off >>= 1)
                ps += __shfl_xor(ps, off, 64);
            lrow[r] = lrow[r] * sc + ps;
            mrow[r] = mn;
            scl[r] = sc;
        }
        #pragma unroll
        for (int n = 0; n < 8; ++n) {
            oacc[n][0] *= scl[0];
            oacc[n][1] *= scl[1];
            oacc[n][2] *= scl[2];
            oacc[n][3] *= scl[3];
        }

        // ---- P -> LDS (per-wave region), re-layout for PV A-fragment ----
        short* pw = pls + w * (16 * PADV);
        #pragma unroll
        for (int t = 0; t < 4; ++t) {
            #pragma unroll
            for (int r = 0; r < 4; ++r) {
                pw[(gq * 4 + r) * PADV + t * 16 + lg] = f2bf(sacc[t][r]);
            }
        }
        asm volatile("s_waitcnt lgkmcnt(0)" ::: "memory");

        // ---- O += P V ----
        #pragma unroll
        for (int kt = 0; kt < 2; ++kt) {
            bf8_t pa = *(const bf8_t*)(&pw[lg * PADV + kt * 32 + gq * 8]);
            #pragma unroll
            for (int n = 0; n < 8; ++n) {
                bf8_t vb = *(const bf8_t*)(&vt[(n * 16 + lg) * PADV + kt * 32 + gq * 8]);
                oacc[n] = __builtin_amdgcn_mfma_f32_16x16x32_bf16(pa, vb, oacc[n], 0, 0, 0);
            }
        }
    }

    // ---- epilogue: normalize and store fp32 ----
    float inv[4];
    #pragma unroll
    for (int r = 0; r < 4; ++r) inv[r] = 1.f / lrow[r];
    float* op = O + base + (size_t)qrow0 * D_DIM;
    #pragma unroll
    for (int n = 0; n < 8; ++n) {
        #pragma unroll
        for (int r = 0; r < 4; ++r) {
            op[(size_t)(gq * 4 + r) * D_DIM + n * 16 + lg] = oacc[n][r] * inv[r];
        }
    }
}

extern "C" void kernel_launch(void* const* d_in, const int* in_sizes, int n_in,
                              void* d_out, int out_size, void* d_ws, size_t ws_size,
                              hipStream_t stream) {
    const float* q = (const float*)d_in[0];
    const float* k = (const float*)d_in[1];
    const float* v = (const float*)d_in[2];
    float* o = (float*)d_out;
    dim3 grid(S_LEN / QT, 4 * 16);   // (q-blocks, B*H)
    attn_fwd<<<grid, 256, 0, stream>>>(q, k, v, o);
}

// Round 2
// 397.799 us; speedup vs baseline: 2.2282x; 2.2282x over previous
//
#include <hip/hip_runtime.h>
#include <hip/hip_bf16.h>
#include <math.h>
#include <stdint.h>

#define S_LEN 2048
#define D_DIM 128

typedef short bf8_t __attribute__((ext_vector_type(8)));   // 8 bf16
typedef float f32x4 __attribute__((ext_vector_type(4)));

__device__ __forceinline__ short f2bf(float f) {
    union { float f; unsigned u; } x; x.f = f;
    unsigned u = x.u;
    u += 0x7FFF + ((u >> 16) & 1);   // RNE
    return (short)(u >> 16);
}
__device__ __forceinline__ float bf2f(short h) {
    union { unsigned u; float f; } x;
    x.u = ((unsigned)(unsigned short)h) << 16;
    return x.f;
}
__device__ __forceinline__ uint32_t pk2(float a, float b) {
    return (uint32_t)(unsigned short)f2bf(a) | ((uint32_t)(unsigned short)f2bf(b) << 16);
}

#define TILE_B 16384
#define WS_KLO 33554432u
#define WS_VT  67108864u
#define WS_NEED 100663296u

typedef const uint32_t __attribute__((address_space(1))) ga_u32;
typedef uint32_t __attribute__((address_space(3))) la_u32;
__device__ __forceinline__ void gload16(void* l, const void* g) {
    __builtin_amdgcn_global_load_lds((ga_u32*)g, (la_u32*)l, 16, 0, 0);
}

// ---- phase 0a: K fp32 -> bf16 hi/lo, swizzled 64x128 tiles ----
__global__ __launch_bounds__(256, 4)
void conv_k(const float* __restrict__ K, char* __restrict__ khi, char* __restrict__ klo)
{
    int gid = blockIdx.x * 256 + threadIdx.x;       // 0 .. 4194303 (float4 index)
    int d0  = (gid & 31) * 4;
    int sg  = gid >> 5;
    int row = sg & 63;
    size_t tile = (size_t)(sg >> 6);                // bh*32 + s/64
    float4 kk = ((const float4*)K)[gid];
    short4 hi, lo;
    hi.x = f2bf(kk.x); lo.x = f2bf(kk.x - bf2f(hi.x));
    hi.y = f2bf(kk.y); lo.y = f2bf(kk.y - bf2f(hi.y));
    hi.z = f2bf(kk.z); lo.z = f2bf(kk.z - bf2f(hi.z));
    hi.w = f2bf(kk.w); lo.w = f2bf(kk.w - bf2f(hi.w));
    uint32_t byte = (uint32_t)((row * 256 + d0 * 2) ^ ((row & 7) << 4));
    *(short4*)(khi + tile * TILE_B + byte) = hi;
    *(short4*)(klo + tile * TILE_B + byte) = lo;
}

// ---- phase 0b: V fp32 -> V^T bf16, swizzled 128x64 tiles ----
__global__ __launch_bounds__(256, 4)
void conv_v(const float* __restrict__ V, char* __restrict__ vt)
{
    size_t tile = blockIdx.x;                       // bh*32 + s/64
    const float* src = V + tile * (64 * 128);
    char* dst = vt + tile * TILE_B;
    #pragma unroll
    for (int it = 0; it < 8; ++it) {
        int idx = it * 256 + threadIdx.x;           // 0..2047
        int d  = idx & 127;
        int k0 = (idx >> 7) * 4;
        short4 o;
        o.x = f2bf(src[(k0 + 0) * 128 + d]);
        o.y = f2bf(src[(k0 + 1) * 128 + d]);
        o.z = f2bf(src[(k0 + 2) * 128 + d]);
        o.w = f2bf(src[(k0 + 3) * 128 + d]);
        uint32_t byte = (uint32_t)((d * 128 + k0 * 2) ^ ((d & 7) << 4));
        *(short4*)(dst + byte) = o;
    }
}

// ---- main: flash attention, swapped QK^T, in-register P ----
__global__ __launch_bounds__(256, 3)
void attn_fast(const float* __restrict__ Q, const char* __restrict__ ws,
               float* __restrict__ O)
{
    __shared__ __align__(16) char lds[49152];   // khi 16K | klo 16K | vt 16K

    const int tid  = threadIdx.x;
    const int w    = tid >> 6;
    const int lane = tid & 63;
    const int lg   = lane & 15;
    const int gq   = lane >> 4;

    const int qblk = blockIdx.x;
    const int bh   = blockIdx.y;
    const size_t base = (size_t)bh * S_LEN * D_DIM;
    const int qrow0 = qblk * 64 + w * 16;

    // Q fragments (hi/lo split) in registers; B-operand layout (col = q = lg)
    bf8_t qhi[4], qlo[4];
    {
        const float* qp = Q + base + (size_t)(qrow0 + lg) * D_DIM;
        #pragma unroll
        for (int c = 0; c < 4; ++c) {
            #pragma unroll
            for (int jj = 0; jj < 2; ++jj) {
                float4 f = *(const float4*)(qp + c * 32 + gq * 8 + jj * 4);
                #pragma unroll
                for (int m = 0; m < 4; ++m) {
                    float fv = (&f.x)[m];
                    short h = f2bf(fv);
                    qhi[c][jj * 4 + m] = h;
                    qlo[c][jj * 4 + m] = f2bf(fv - bf2f(h));
                }
            }
        }
    }

    f32x4 oacc[8];
    #pragma unroll
    for (int n = 0; n < 8; ++n) oacc[n] = (f32x4){0.f, 0.f, 0.f, 0.f};
    float m_run = -INFINITY, l_run = 0.f;

    const char* kh_t = ws + (size_t)(bh * 32) * TILE_B;
    const char* kl_t = ws + WS_KLO + (size_t)(bh * 32) * TILE_B;
    const char* vt_t = ws + WS_VT + (size_t)(bh * 32) * TILE_B;
    const int sw = (lg & 7) << 4;

    for (int t6 = 0; t6 < 32; ++t6) {
        __syncthreads();   // previous tile's reads complete
        // ---- stage khi/klo/vt via global_load_lds (linear, pre-swizzled src) ----
        #pragma unroll
        for (int j = 0; j < 4; ++j) {
            const int off = j * 4096 + w * 1024;
            gload16(lds + off,         kh_t + off + lane * 16);
            gload16(lds + 16384 + off, kl_t + off + lane * 16);
            gload16(lds + 32768 + off, vt_t + off + lane * 16);
        }
        kh_t += TILE_B; kl_t += TILE_B; vt_t += TILE_B;
        __syncthreads();   // implicit vmcnt(0) drain before barrier

        // ---- S^T = K Q^T : lane holds S[k=16t+4gq+r][q=lg] ----
        f32x4 sacc[4];
        #pragma unroll
        for (int t = 0; t < 4; ++t) sacc[t] = (f32x4){0.f, 0.f, 0.f, 0.f};
        #pragma unroll
        for (int t = 0; t < 4; ++t) {
            const int rb = (t * 16 + lg) * 256;
            #pragma unroll
            for (int c = 0; c < 4; ++c) {
                const int byte = (rb + c * 64 + gq * 16) ^ sw;
                bf8_t khf = *(const bf8_t*)(lds + byte);
                bf8_t klf = *(const bf8_t*)(lds + 16384 + byte);
                sacc[t] = __builtin_amdgcn_mfma_f32_16x16x32_bf16(khf, qhi[c], sacc[t], 0, 0, 0);
                sacc[t] = __builtin_amdgcn_mfma_f32_16x16x32_bf16(klf, qhi[c], sacc[t], 0, 0, 0);
                sacc[t] = __builtin_amdgcn_mfma_f32_16x16x32_bf16(khf, qlo[c], sacc[t], 0, 0, 0);
            }
        }

        // ---- online softmax (row q = lg lives across the 4 gq groups) ----
        float tm = sacc[0][0];
        #pragma unroll
        for (int t = 0; t < 4; ++t)
            #pragma unroll
            for (int r = 0; r < 4; ++r) tm = fmaxf(tm, sacc[t][r]);
        tm = fmaxf(tm, __shfl_xor(tm, 16));
        tm = fmaxf(tm, __shfl_xor(tm, 32));
        const float mn = fmaxf(m_run, tm);
        const float sc = __expf(m_run - mn);
        float ps = 0.f;
        #pragma unroll
        for (int t = 0; t < 4; ++t)
            #pragma unroll
            for (int r = 0; r < 4; ++r) {
                float p = __expf(sacc[t][r] - mn);
                sacc[t][r] = p;
                ps += p;
            }
        ps += __shfl_xor(ps, 16);
        ps += __shfl_xor(ps, 32);
        l_run = l_run * sc + ps;
        m_run = mn;
        float scq[4];
        #pragma unroll
        for (int r = 0; r < 4; ++r) scq[r] = __shfl(sc, gq * 4 + r);
        #pragma unroll
        for (int n = 0; n < 8; ++n) {
            oacc[n][0] *= scq[0]; oacc[n][1] *= scq[1];
            oacc[n][2] *= scq[2]; oacc[n][3] *= scq[3];
        }

        // ---- pack P to bf16 pairs; exchange to A-fragment layout in-register ----
        uint32_t dw[4][2];
        #pragma unroll
        for (int t = 0; t < 4; ++t) {
            dw[t][0] = pk2(sacc[t][0], sacc[t][1]);
            dw[t][1] = pk2(sacc[t][2], sacc[t][3]);
        }
        const int tclass = gq >> 1;
        const int sgl = (2 * (gq & 1)) * 16 + lg;
        #pragma unroll
        for (int kt = 0; kt < 2; ++kt) {
            uint32_t paw[4];
            #pragma unroll
            for (int wd = 0; wd < 4; ++wd) {
                const int src = sgl + (wd >> 1) * 16;
                uint32_t vA = (uint32_t)__shfl((int)dw[2 * kt][wd & 1], src);
                uint32_t vB = (uint32_t)__shfl((int)dw[2 * kt + 1][wd & 1], src);
                paw[wd] = tclass ? vB : vA;
            }
            union { uint32_t u[4]; bf8_t v; } pu;
            pu.u[0] = paw[0]; pu.u[1] = paw[1]; pu.u[2] = paw[2]; pu.u[3] = paw[3];
            bf8_t pa = pu.v;
            #pragma unroll
            for (int n = 0; n < 8; ++n) {
                const int byte = ((n * 16 + lg) * 128 + kt * 64 + gq * 16) ^ sw;
                bf8_t vb = *(const bf8_t*)(lds + 32768 + byte);
                oacc[n] = __builtin_amdgcn_mfma_f32_16x16x32_bf16(pa, vb, oacc[n], 0, 0, 0);
            }
        }
    }

    // ---- epilogue ----
    const float inv_own = 1.f / l_run;
    float invq[4];
    #pragma unroll
    for (int r = 0; r < 4; ++r) invq[r] = __shfl(inv_own, gq * 4 + r);
    float* op = O + base + (size_t)qrow0 * D_DIM;
    #pragma unroll
    for (int n = 0; n < 8; ++n)
        #pragma unroll
        for (int r = 0; r < 4; ++r)
            op[(size_t)(gq * 4 + r) * D_DIM + n * 16 + lg] = oacc[n][r] * invq[r];
}

// ================= fallback (round-1 kernel, passes without ws) =================
#define PADK 136
#define PADV 72
#define LDS_SHORTS 31232

__global__ __launch_bounds__(256, 2)
void attn_fwd_fb(const float* __restrict__ Q, const float* __restrict__ K,
                 const float* __restrict__ V, float* __restrict__ O)
{
    __shared__ short lds[LDS_SHORTS];
    short* khi = lds;
    short* klo = lds + 8704;
    short* vt  = lds + 17408;
    short* pls = lds + 26624;

    const int tid  = threadIdx.x;
    const int w    = tid >> 6;
    const int lane = tid & 63;
    const int lg   = lane & 15;
    const int gq   = lane >> 4;
    const int qblk = blockIdx.x;
    const int bh   = blockIdx.y;
    const size_t base = (size_t)bh * S_LEN * D_DIM;
    const int qrow0 = qblk * 64 + w * 16;

    bf8_t qhi[4], qlo[4];
    {
        const float* qp = Q + base + (size_t)(qrow0 + lg) * D_DIM;
        #pragma unroll
        for (int c = 0; c < 4; ++c) {
            const int d0 = c * 32 + gq * 8;
            #pragma unroll
            for (int j = 0; j < 8; ++j) {
                float f = qp[d0 + j];
                short h = f2bf(f);
                qhi[c][j] = h;
                qlo[c][j] = f2bf(f - bf2f(h));
            }
        }
    }

    f32x4 oacc[8];
    #pragma unroll
    for (int n = 0; n < 8; ++n) oacc[n] = (f32x4){0.f, 0.f, 0.f, 0.f};
    float mrow[4] = {-INFINITY, -INFINITY, -INFINITY, -INFINITY};
    float lrow[4] = {0.f, 0.f, 0.f, 0.f};

    for (int kv = 0; kv < S_LEN; kv += 64) {
        __syncthreads();
        {
            const float4* kg = (const float4*)(K + base + (size_t)kv * D_DIM);
            const float4* vg = (const float4*)(V + base + (size_t)kv * D_DIM);
            #pragma unroll
            for (int it = 0; it < 8; ++it) {
                const int f4  = it * 256 + tid;
                const int row = f4 >> 5;
                const int d   = (f4 & 31) * 4;
                float4 kk = kg[f4];
                float4 vv = vg[f4];
                short h0 = f2bf(kk.x), h1 = f2bf(kk.y), h2 = f2bf(kk.z), h3 = f2bf(kk.w);
                short4 hw; hw.x = h0; hw.y = h1; hw.z = h2; hw.w = h3;
                *(short4*)(&khi[row * PADK + d]) = hw;
                short4 lw;
                lw.x = f2bf(kk.x - bf2f(h0));
                lw.y = f2bf(kk.y - bf2f(h1));
                lw.z = f2bf(kk.z - bf2f(h2));
                lw.w = f2bf(kk.w - bf2f(h3));
                *(short4*)(&klo[row * PADK + d]) = lw;
                vt[(d + 0) * PADV + row] = f2bf(vv.x);
                vt[(d + 1) * PADV + row] = f2bf(vv.y);
                vt[(d + 2) * PADV + row] = f2bf(vv.z);
                vt[(d + 3) * PADV + row] = f2bf(vv.w);
            }
        }
        __syncthreads();

        f32x4 sacc[4];
        #pragma unroll
        for (int t = 0; t < 4; ++t) sacc[t] = (f32x4){0.f, 0.f, 0.f, 0.f};
        #pragma unroll
        for (int t = 0; t < 4; ++t) {
            const int krow = t * 16 + lg;
            #pragma unroll
            for (int c = 0; c < 4; ++c) {
                bf8_t kh = *(const bf8_t*)(&khi[krow * PADK + c * 32 + gq * 8]);
                bf8_t kl = *(const bf8_t*)(&klo[krow * PADK + c * 32 + gq * 8]);
                sacc[t] = __builtin_amdgcn_mfma_f32_16x16x32_bf16(qhi[c], kh, sacc[t], 0, 0, 0);
                sacc[t] = __builtin_amdgcn_mfma_f32_16x16x32_bf16(qlo[c], kh, sacc[t], 0, 0, 0);
                sacc[t] = __builtin_amdgcn_mfma_f32_16x16x32_bf16(qhi[c], kl, sacc[t], 0, 0, 0);
            }
        }

        float scl[4];
        #pragma unroll
        for (int r = 0; r < 4; ++r) {
            float tm = fmaxf(fmaxf(sacc[0][r], sacc[1][r]),
                             fmaxf(sacc[2][r], sacc[3][r]));
            #pragma unroll
            for (int off = 8; off >= 1; off >>= 1)
                tm = fmaxf(tm, __shfl_xor(tm, off, 64));
            const float mn = fmaxf(mrow[r], tm);
            const float sc = __expf(mrow[r] - mn);
            float ps = 0.f;
            #pragma unroll
            for (int t = 0; t < 4; ++t) {
                float p = __expf(sacc[t][r] - mn);
                sacc[t][r] = p;
                ps += p;
            }
            #pragma unroll
            for (int off = 8; off >= 1; off >>= 1)
                ps += __shfl_xor(ps, off, 64);
            lrow[r] = lrow[r] * sc + ps;
            mrow[r] = mn;
            scl[r] = sc;
        }
        #pragma unroll
        for (int n = 0; n < 8; ++n) {
            oacc[n][0] *= scl[0];
            oacc[n][1] *= scl[1];
            oacc[n][2] *= scl[2];
            oacc[n][3] *= scl[3];
        }

        short* pw = pls + w * (16 * PADV);
        #pragma unroll
        for (int t = 0; t < 4; ++t)
            #pragma unroll
            for (int r = 0; r < 4; ++r)
                pw[(gq * 4 + r) * PADV + t * 16 + lg] = f2bf(sacc[t][r]);
        asm volatile("s_waitcnt lgkmcnt(0)" ::: "memory");

        #pragma unroll
        for (int kt = 0; kt < 2; ++kt) {
            bf8_t pa = *(const bf8_t*)(&pw[lg * PADV + kt * 32 + gq * 8]);
            #pragma unroll
            for (int n = 0; n < 8; ++n) {
                bf8_t vb = *(const bf8_t*)(&vt[(n * 16 + lg) * PADV + kt * 32 + gq * 8]);
                oacc[n] = __builtin_amdgcn_mfma_f32_16x16x32_bf16(pa, vb, oacc[n], 0, 0, 0);
            }
        }
    }

    float inv[4];
    #pragma unroll
    for (int r = 0; r < 4; ++r) inv[r] = 1.f / lrow[r];
    float* op = O + base + (size_t)qrow0 * D_DIM;
    #pragma unroll
    for (int n = 0; n < 8; ++n)
        #pragma unroll
        for (int r = 0; r < 4; ++r)
            op[(size_t)(gq * 4 + r) * D_DIM + n * 16 + lg] = oacc[n][r] * inv[r];
}

extern "C" void kernel_launch(void* const* d_in, const int* in_sizes, int n_in,
                              void* d_out, int out_size, void* d_ws, size_t ws_size,
                              hipStream_t stream) {
    const float* q = (const float*)d_in[0];
    const float* k = (const float*)d_in[1];
    const float* v = (const float*)d_in[2];
    float* o = (float*)d_out;
    if (ws_size >= (size_t)WS_NEED) {
        char* ws = (char*)d_ws;
        conv_k<<<16384, 256, 0, stream>>>(k, ws, ws + WS_KLO);
        conv_v<<<2048, 256, 0, stream>>>(v, ws + WS_VT);
        attn_fast<<<dim3(32, 64), 256, 0, stream>>>(q, ws, o);
    } else {
        attn_fwd_fb<<<dim3(32, 64), 256, 0, stream>>>(q, k, v, o);
    }
}

// Round 4
// 305.475 us; speedup vs baseline: 2.9016x; 1.3022x over previous
//
#include <hip/hip_runtime.h>
#include <hip/hip_bf16.h>
#include <math.h>
#include <stdint.h>

#define S_LEN 2048
#define D_DIM 128

typedef _Float16 f16x8 __attribute__((ext_vector_type(8)));
typedef _Float16 f16x2 __attribute__((ext_vector_type(2)));
typedef __fp16  fp16x2 __attribute__((ext_vector_type(2)));   // cvt_pkrtz return type
typedef short bf8_t __attribute__((ext_vector_type(8)));
typedef float f32x4 __attribute__((ext_vector_type(4)));
typedef _Float16 f16_t;

__device__ __forceinline__ short f2bf(float f) {
    union { float f; unsigned u; } x; x.f = f;
    unsigned u = x.u;
    u += 0x7FFF + ((u >> 16) & 1);
    return (short)(u >> 16);
}
__device__ __forceinline__ float bf2f(short h) {
    union { unsigned u; float f; } x;
    x.u = ((unsigned)(unsigned short)h) << 16;
    return x.f;
}
__device__ __forceinline__ uint32_t pkf16(float a, float b) {
    union { fp16x2 h; uint32_t u; } x;
    x.h = __builtin_amdgcn_cvt_pkrtz(a, b);
    return x.u;
}

#define TILE_B 16384
#define WS_VT  33554432u
#define WS_NEED 67108864u

typedef const uint32_t __attribute__((address_space(1))) ga_u32;
typedef uint32_t __attribute__((address_space(3))) la_u32;
__device__ __forceinline__ void gload16(void* l, const void* g) {
    __builtin_amdgcn_global_load_lds((ga_u32*)g, (la_u32*)l, 16, 0, 0);
}

// ---- phase 0a: K fp32 -> f16, swizzled 64x128 tiles ----
__global__ __launch_bounds__(256, 4)
void conv_k(const float* __restrict__ K, char* __restrict__ kf)
{
    int gid = blockIdx.x * 256 + threadIdx.x;       // float4 index
    int d0  = (gid & 31) * 4;
    int sg  = gid >> 5;
    int row = sg & 63;
    size_t tile = (size_t)(sg >> 6);                // bh*32 + s/64
    float4 kk = ((const float4*)K)[gid];
    uint32_t a = pkf16(kk.x, kk.y);
    uint32_t b = pkf16(kk.z, kk.w);
    uint32_t byte = (uint32_t)((row * 256 + d0 * 2) ^ ((row & 7) << 4));
    char* p = kf + tile * TILE_B + byte;
    *(uint32_t*)(p)     = a;
    *(uint32_t*)(p + 4) = b;
}

// ---- phase 0b: V fp32 -> V^T f16, swizzled 128x64 tiles ----
__global__ __launch_bounds__(256, 4)
void conv_v(const float* __restrict__ V, char* __restrict__ vt)
{
    size_t tile = blockIdx.x;                       // bh*32 + s/64
    const float* src = V + tile * (64 * 128);
    char* dst = vt + tile * TILE_B;
    #pragma unroll
    for (int it = 0; it < 8; ++it) {
        int idx = it * 256 + threadIdx.x;           // 0..2047
        int d  = idx & 127;
        int k0 = (idx >> 7) * 4;
        uint32_t a = pkf16(src[(k0 + 0) * 128 + d], src[(k0 + 1) * 128 + d]);
        uint32_t b = pkf16(src[(k0 + 2) * 128 + d], src[(k0 + 3) * 128 + d]);
        uint32_t byte = (uint32_t)((d * 128 + k0 * 2) ^ ((d & 7) << 4));
        *(uint32_t*)(dst + byte)     = a;
        *(uint32_t*)(dst + byte + 4) = b;
    }
}

// ---- main: flash attention f16, double-buffered staging ----
__global__ __launch_bounds__(256, 2)
void attn_f16(const float* __restrict__ Q, const char* __restrict__ ws,
              float* __restrict__ O)
{
    __shared__ __align__(16) char lds[65536];  // buf: [kf 16K | vt 16K] x2

    const int tid  = threadIdx.x;
    const int w    = tid >> 6;
    const int lane = tid & 63;
    const int lg   = lane & 15;
    const int gq   = lane >> 4;

    // chunked XCD swizzle: XCD x gets new-ids [x*256, x*256+256) = 8 heads
    const int fid  = blockIdx.x;
    const int nid  = (fid & 7) * 256 + (fid >> 3);
    const int qblk = nid & 31;
    const int bh   = nid >> 5;

    const size_t base = (size_t)bh * S_LEN * D_DIM;
    const int qrow0 = qblk * 64 + w * 16;

    // Q f16 fragments (B-operand layout: col=q=lg, k-offset=gq*8)
    f16x8 qf[4];
    {
        const float* qp = Q + base + (size_t)(qrow0 + lg) * D_DIM;
        #pragma unroll
        for (int c = 0; c < 4; ++c) {
            #pragma unroll
            for (int jj = 0; jj < 2; ++jj) {
                float4 f = *(const float4*)(qp + c * 32 + gq * 8 + jj * 4);
                qf[c][jj * 4 + 0] = (f16_t)f.x;
                qf[c][jj * 4 + 1] = (f16_t)f.y;
                qf[c][jj * 4 + 2] = (f16_t)f.z;
                qf[c][jj * 4 + 3] = (f16_t)f.w;
            }
        }
    }

    f32x4 oacc[8];
    #pragma unroll
    for (int n = 0; n < 8; ++n) oacc[n] = (f32x4){0.f, 0.f, 0.f, 0.f};
    float m_run = -INFINITY, l_run = 0.f;

    const char* kf_t = ws + (size_t)(bh * 32) * TILE_B;
    const char* vt_t = ws + WS_VT + (size_t)(bh * 32) * TILE_B;
    const int sw = (lg & 7) << 4;

    // prologue: stage tile 0 into buf0
    #pragma unroll
    for (int j = 0; j < 4; ++j) {
        const int off = j * 4096 + w * 1024;
        gload16(lds + off,         kf_t + off + lane * 16);
        gload16(lds + 16384 + off, vt_t + off + lane * 16);
    }
    __syncthreads();

    int bo = 0;
    for (int t6 = 0; t6 < 32; ++t6) {
        // ---- prefetch tile t6+1 into the other buffer ----
        if (t6 < 31) {
            const char* kn = kf_t + (size_t)(t6 + 1) * TILE_B;
            const char* vn = vt_t + (size_t)(t6 + 1) * TILE_B;
            const int ob = bo ^ 32768;
            #pragma unroll
            for (int j = 0; j < 4; ++j) {
                const int off = j * 4096 + w * 1024;
                gload16(lds + ob + off,         kn + off + lane * 16);
                gload16(lds + ob + 16384 + off, vn + off + lane * 16);
            }
        }

        // ---- S^T = K Q^T : lane holds S[k=16t+4gq+r][q=lg] ----
        f32x4 sacc[4];
        #pragma unroll
        for (int t = 0; t < 4; ++t) sacc[t] = (f32x4){0.f, 0.f, 0.f, 0.f};
        #pragma unroll
        for (int t = 0; t < 4; ++t) {
            const int rb = (t * 16 + lg) * 256;
            #pragma unroll
            for (int c = 0; c < 4; ++c) {
                const int byte = (rb + c * 64 + gq * 16) ^ sw;
                f16x8 kff = *(const f16x8*)(lds + bo + byte);
                sacc[t] = __builtin_amdgcn_mfma_f32_16x16x32_f16(kff, qf[c], sacc[t], 0, 0, 0);
            }
        }

        // ---- online softmax (row q = lg spread across gq groups) ----
        float tm = sacc[0][0];
        #pragma unroll
        for (int t = 0; t < 4; ++t)
            #pragma unroll
            for (int r = 0; r < 4; ++r) tm = fmaxf(tm, sacc[t][r]);
        tm = fmaxf(tm, __shfl_xor(tm, 16));
        tm = fmaxf(tm, __shfl_xor(tm, 32));
        const float mn = fmaxf(m_run, tm);
        const float sc = __expf(m_run - mn);
        float ps = 0.f;
        #pragma unroll
        for (int t = 0; t < 4; ++t)
            #pragma unroll
            for (int r = 0; r < 4; ++r) {
                float p = __expf(sacc[t][r] - mn);
                sacc[t][r] = p;
                ps += p;
            }
        ps += __shfl_xor(ps, 16);
        ps += __shfl_xor(ps, 32);
        l_run = l_run * sc + ps;
        m_run = mn;
        float scq[4];
        #pragma unroll
        for (int r = 0; r < 4; ++r) scq[r] = __shfl(sc, gq * 4 + r);
        #pragma unroll
        for (int n = 0; n < 8; ++n) {
            oacc[n][0] *= scq[0]; oacc[n][1] *= scq[1];
            oacc[n][2] *= scq[2]; oacc[n][3] *= scq[3];
        }

        // ---- pack P to f16 pairs; exchange to A-fragment layout in-register ----
        uint32_t dw[4][2];
        #pragma unroll
        for (int t = 0; t < 4; ++t) {
            dw[t][0] = pkf16(sacc[t][0], sacc[t][1]);
            dw[t][1] = pkf16(sacc[t][2], sacc[t][3]);
        }
        const int tclass = gq >> 1;
        const int sgl = (2 * (gq & 1)) * 16 + lg;
        #pragma unroll
        for (int kt = 0; kt < 2; ++kt) {
            uint32_t paw[4];
            #pragma unroll
            for (int wd = 0; wd < 4; ++wd) {
                const int src = sgl + (wd >> 1) * 16;
                uint32_t vA = (uint32_t)__shfl((int)dw[2 * kt][wd & 1], src);
                uint32_t vB = (uint32_t)__shfl((int)dw[2 * kt + 1][wd & 1], src);
                paw[wd] = tclass ? vB : vA;
            }
            union { uint32_t u[4]; f16x8 v; } pu;
            pu.u[0] = paw[0]; pu.u[1] = paw[1]; pu.u[2] = paw[2]; pu.u[3] = paw[3];
            f16x8 pa = pu.v;
            #pragma unroll
            for (int n = 0; n < 8; ++n) {
                const int byte = ((n * 16 + lg) * 128 + kt * 64 + gq * 16) ^ sw;
                f16x8 vb = *(const f16x8*)(lds + bo + 16384 + byte);
                oacc[n] = __builtin_amdgcn_mfma_f32_16x16x32_f16(pa, vb, oacc[n], 0, 0, 0);
            }
        }

        // drain prefetch + protect buffers (syncthreads implies full waitcnt)
        __syncthreads();
        bo ^= 32768;
    }

    // ---- epilogue ----
    const float inv_own = 1.f / l_run;
    float invq[4];
    #pragma unroll
    for (int r = 0; r < 4; ++r) invq[r] = __shfl(inv_own, gq * 4 + r);
    float* op = O + base + (size_t)qrow0 * D_DIM;
    #pragma unroll
    for (int n = 0; n < 8; ++n)
        #pragma unroll
        for (int r = 0; r < 4; ++r)
            op[(size_t)(gq * 4 + r) * D_DIM + n * 16 + lg] = oacc[n][r] * invq[r];
}

// ================= fallback (round-1 kernel, passes without ws) =================
#define PADK 136
#define PADV 72
#define LDS_SHORTS 31232

__global__ __launch_bounds__(256, 2)
void attn_fwd_fb(const float* __restrict__ Q, const float* __restrict__ K,
                 const float* __restrict__ V, float* __restrict__ O)
{
    __shared__ short lds[LDS_SHORTS];
    short* khi = lds;
    short* klo = lds + 8704;
    short* vt  = lds + 17408;
    short* pls = lds + 26624;

    const int tid  = threadIdx.x;
    const int w    = tid >> 6;
    const int lane = tid & 63;
    const int lg   = lane & 15;
    const int gq   = lane >> 4;
    const int qblk = blockIdx.x;
    const int bh   = blockIdx.y;
    const size_t base = (size_t)bh * S_LEN * D_DIM;
    const int qrow0 = qblk * 64 + w * 16;

    bf8_t qhi[4], qlo[4];
    {
        const float* qp = Q + base + (size_t)(qrow0 + lg) * D_DIM;
        #pragma unroll
        for (int c = 0; c < 4; ++c) {
            const int d0 = c * 32 + gq * 8;
            #pragma unroll
            for (int j = 0; j < 8; ++j) {
                float f = qp[d0 + j];
                short h = f2bf(f);
                qhi[c][j] = h;
                qlo[c][j] = f2bf(f - bf2f(h));
            }
        }
    }

    f32x4 oacc[8];
    #pragma unroll
    for (int n = 0; n < 8; ++n) oacc[n] = (f32x4){0.f, 0.f, 0.f, 0.f};
    float mrow[4] = {-INFINITY, -INFINITY, -INFINITY, -INFINITY};
    float lrow[4] = {0.f, 0.f, 0.f, 0.f};

    for (int kv = 0; kv < S_LEN; kv += 64) {
        __syncthreads();
        {
            const float4* kg = (const float4*)(K + base + (size_t)kv * D_DIM);
            const float4* vg = (const float4*)(V + base + (size_t)kv * D_DIM);
            #pragma unroll
            for (int it = 0; it < 8; ++it) {
                const int f4  = it * 256 + tid;
                const int row = f4 >> 5;
                const int d   = (f4 & 31) * 4;
                float4 kk = kg[f4];
                float4 vv = vg[f4];
                short h0 = f2bf(kk.x), h1 = f2bf(kk.y), h2 = f2bf(kk.z), h3 = f2bf(kk.w);
                short4 hw; hw.x = h0; hw.y = h1; hw.z = h2; hw.w = h3;
                *(short4*)(&khi[row * PADK + d]) = hw;
                short4 lw;
                lw.x = f2bf(kk.x - bf2f(h0));
                lw.y = f2bf(kk.y - bf2f(h1));
                lw.z = f2bf(kk.z - bf2f(h2));
                lw.w = f2bf(kk.w - bf2f(h3));
                *(short4*)(&klo[row * PADK + d]) = lw;
                vt[(d + 0) * PADV + row] = f2bf(vv.x);
                vt[(d + 1) * PADV + row] = f2bf(vv.y);
                vt[(d + 2) * PADV + row] = f2bf(vv.z);
                vt[(d + 3) * PADV + row] = f2bf(vv.w);
            }
        }
        __syncthreads();

        f32x4 sacc[4];
        #pragma unroll
        for (int t = 0; t < 4; ++t) sacc[t] = (f32x4){0.f, 0.f, 0.f, 0.f};
        #pragma unroll
        for (int t = 0; t < 4; ++t) {
            const int krow = t * 16 + lg;
            #pragma unroll
            for (int c = 0; c < 4; ++c) {
                bf8_t kh = *(const bf8_t*)(&khi[krow * PADK + c * 32 + gq * 8]);
                bf8_t kl = *(const bf8_t*)(&klo[krow * PADK + c * 32 + gq * 8]);
                sacc[t] = __builtin_amdgcn_mfma_f32_16x16x32_bf16(qhi[c], kh, sacc[t], 0, 0, 0);
                sacc[t] = __builtin_amdgcn_mfma_f32_16x16x32_bf16(qlo[c], kh, sacc[t], 0, 0, 0);
                sacc[t] = __builtin_amdgcn_mfma_f32_16x16x32_bf16(qhi[c], kl, sacc[t], 0, 0, 0);
            }
        }

        float scl[4];
        #pragma unroll
        for (int r = 0; r < 4; ++r) {
            float tm = fmaxf(fmaxf(sacc[0][r], sacc[1][r]),
                             fmaxf(sacc[2][r], sacc[3][r]));
            #pragma unroll
            for (int off = 8; off >= 1; off >>= 1)
                tm = fmaxf(tm, __shfl_xor(tm, off, 64));
            const float mn = fmaxf(mrow[r], tm);
            const float sc = __expf(mrow[r] - mn);
            float ps = 0.f;
            #pragma unroll
            for (int t = 0; t < 4; ++t) {
                float p = __expf(sacc[t][r] - mn);
                sacc[t][r] = p;
                ps += p;
            }
            #pragma unroll
            for (int off = 8; off >= 1; off >>= 1)
                ps += __shfl_xor(ps, off, 64);
            lrow[r] = lrow[r] * sc + ps;
            mrow[r] = mn;
            scl[r] = sc;
        }
        #pragma unroll
        for (int n = 0; n < 8; ++n) {
            oacc[n][0] *= scl[0];
            oacc[n][1] *= scl[1];
            oacc[n][2] *= scl[2];
            oacc[n][3] *= scl[3];
        }

        short* pw = pls + w * (16 * PADV);
        #pragma unroll
        for (int t = 0; t < 4; ++t)
            #pragma unroll
            for (int r = 0; r < 4; ++r)
                pw[(gq * 4 + r) * PADV + t * 16 + lg] = f2bf(sacc[t][r]);
        asm volatile("s_waitcnt lgkmcnt(0)" ::: "memory");

        #pragma unroll
        for (int kt = 0; kt < 2; ++kt) {
            bf8_t pa = *(const bf8_t*)(&pw[lg * PADV + kt * 32 + gq * 8]);
            #pragma unroll
            for (int n = 0; n < 8; ++n) {
                bf8_t vb = *(const bf8_t*)(&vt[(n * 16 + lg) * PADV + kt * 32 + gq * 8]);
                oacc[n] = __builtin_amdgcn_mfma_f32_16x16x32_bf16(pa, vb, oacc[n], 0, 0, 0);
            }
        }
    }

    float inv[4];
    #pragma unroll
    for (int r = 0; r < 4; ++r) inv[r] = 1.f / lrow[r];
    float* op = O + base + (size_t)qrow0 * D_DIM;
    #pragma unroll
    for (int n = 0; n < 8; ++n)
        #pragma unroll
        for (int r = 0; r < 4; ++r)
            op[(size_t)(gq * 4 + r) * D_DIM + n * 16 + lg] = oacc[n][r] * inv[r];
}

extern "C" void kernel_launch(void* const* d_in, const int* in_sizes, int n_in,
                              void* d_out, int out_size, void* d_ws, size_t ws_size,
                              hipStream_t stream) {
    const float* q = (const float*)d_in[0];
    const float* k = (const float*)d_in[1];
    const float* v = (const float*)d_in[2];
    float* o = (float*)d_out;
    if (ws_size >= (size_t)WS_NEED) {
        char* ws = (char*)d_ws;
        conv_k<<<16384, 256, 0, stream>>>(k, ws);
        conv_v<<<2048, 256, 0, stream>>>(v, ws + WS_VT);
        attn_f16<<<2048, 256, 0, stream>>>(q, ws, o);
    } else {
        attn_fwd_fb<<<dim3(32, 64), 256, 0, stream>>>(q, k, v, o);
    }
}

// Round 5
// 254.982 us; speedup vs baseline: 3.4762x; 1.1980x over previous
//
#include <hip/hip_runtime.h>
#include <hip/hip_bf16.h>
#include <math.h>
#include <stdint.h>

#define S_LEN 2048
#define D_DIM 128

typedef _Float16 f16x8 __attribute__((ext_vector_type(8)));
typedef __fp16  fp16x2 __attribute__((ext_vector_type(2)));   // cvt_pkrtz return type
typedef short bf8_t __attribute__((ext_vector_type(8)));
typedef float f32x4 __attribute__((ext_vector_type(4)));
typedef _Float16 f16_t;

__device__ __forceinline__ short f2bf(float f) {
    union { float f; unsigned u; } x; x.f = f;
    unsigned u = x.u;
    u += 0x7FFF + ((u >> 16) & 1);
    return (short)(u >> 16);
}
__device__ __forceinline__ float bf2f(short h) {
    union { unsigned u; float f; } x;
    x.u = ((unsigned)(unsigned short)h) << 16;
    return x.f;
}
__device__ __forceinline__ uint32_t pkf16(float a, float b) {
    union { fp16x2 h; uint32_t u; } x;
    x.h = __builtin_amdgcn_cvt_pkrtz(a, b);
    return x.u;
}

#define TILE_B 16384
#define WS_VT  33554432u
#define WS_NEED 67108864u

typedef const uint32_t __attribute__((address_space(1))) ga_u32;
typedef uint32_t __attribute__((address_space(3))) la_u32;
__device__ __forceinline__ void gload16(void* l, const void* g) {
    __builtin_amdgcn_global_load_lds((ga_u32*)g, (la_u32*)l, 16, 0, 0);
}

// ---- phase 0: K -> f16 swizzled 64x128 tiles, V -> V^T f16 swizzled tiles ----
__global__ __launch_bounds__(256, 4)
void conv_kv(const float* __restrict__ K, const float* __restrict__ V,
             char* __restrict__ kf, char* __restrict__ vt)
{
    size_t tile = blockIdx.x;                       // bh*32 + s/64
    const float4* kg = (const float4*)(K + tile * (64 * 128));
    char* kd = kf + tile * TILE_B;
    #pragma unroll
    for (int it = 0; it < 8; ++it) {
        int idx = it * 256 + threadIdx.x;           // float4 index in tile
        int row = idx >> 5;
        int d0  = (idx & 31) * 4;
        float4 kk = kg[idx];
        uint32_t a = pkf16(kk.x, kk.y);
        uint32_t b = pkf16(kk.z, kk.w);
        uint32_t byte = (uint32_t)((row * 256 + d0 * 2) ^ ((row & 7) << 4));
        *(uint32_t*)(kd + byte)     = a;
        *(uint32_t*)(kd + byte + 4) = b;
    }
    const float* vs = V + tile * (64 * 128);
    char* vd = vt + tile * TILE_B;
    #pragma unroll
    for (int it = 0; it < 8; ++it) {
        int idx = it * 256 + threadIdx.x;
        int d  = idx & 127;
        int k0 = (idx >> 7) * 4;
        uint32_t a = pkf16(vs[(k0 + 0) * 128 + d], vs[(k0 + 1) * 128 + d]);
        uint32_t b = pkf16(vs[(k0 + 2) * 128 + d], vs[(k0 + 3) * 128 + d]);
        uint32_t byte = (uint32_t)((d * 128 + k0 * 2) ^ ((d & 7) << 4));
        *(uint32_t*)(vd + byte)     = a;
        *(uint32_t*)(vd + byte + 4) = b;
    }
}

// ---- main: flash attention f16, 8 waves/block, double-buffered staging ----
__global__ __launch_bounds__(512, 4)
void attn_f16(const float* __restrict__ Q, const char* __restrict__ ws,
              float* __restrict__ O)
{
    __shared__ __align__(16) char lds[65536];  // buf: [kf 16K | vt 16K] x2

    const int tid  = threadIdx.x;
    const int w    = tid >> 6;      // 0..7
    const int lane = tid & 63;
    const int lg   = lane & 15;
    const int gq   = lane >> 4;

    // chunked XCD swizzle: each XCD gets 128 consecutive new-ids = 2 heads
    const int fid  = blockIdx.x;               // 0..1023
    const int nid  = (fid & 7) * 128 + (fid >> 3);
    const int qblk = nid & 15;
    const int bh   = nid >> 4;

    const size_t base = (size_t)bh * S_LEN * D_DIM;
    const int qrow0 = qblk * 128 + w * 16;

    // Q f16 fragments (B-operand layout: col=q=lg, k-offset=gq*8)
    f16x8 qf[4];
    {
        const float* qp = Q + base + (size_t)(qrow0 + lg) * D_DIM;
        #pragma unroll
        for (int c = 0; c < 4; ++c) {
            #pragma unroll
            for (int jj = 0; jj < 2; ++jj) {
                float4 f = *(const float4*)(qp + c * 32 + gq * 8 + jj * 4);
                qf[c][jj * 4 + 0] = (f16_t)f.x;
                qf[c][jj * 4 + 1] = (f16_t)f.y;
                qf[c][jj * 4 + 2] = (f16_t)f.z;
                qf[c][jj * 4 + 3] = (f16_t)f.w;
            }
        }
    }

    f32x4 oacc[8];
    #pragma unroll
    for (int n = 0; n < 8; ++n) oacc[n] = (f32x4){0.f, 0.f, 0.f, 0.f};
    float m_run = -INFINITY, l_run = 0.f;

    const char* kf_t = ws + (size_t)(bh * 32) * TILE_B;
    const char* vt_t = ws + WS_VT + (size_t)(bh * 32) * TILE_B;
    const int sw = (lg & 7) << 4;

    // prologue: stage tile 0 into buf0 (512 threads x 2 loads x 16B = 16KB each)
    #pragma unroll
    for (int j = 0; j < 2; ++j) {
        const int off = j * 8192 + w * 1024;
        gload16(lds + off,         kf_t + off + lane * 16);
        gload16(lds + 16384 + off, vt_t + off + lane * 16);
    }
    __syncthreads();

    int bo = 0;
    for (int t6 = 0; t6 < 32; ++t6) {
        // ---- prefetch tile t6+1 into the other buffer ----
        if (t6 < 31) {
            const char* kn = kf_t + (size_t)(t6 + 1) * TILE_B;
            const char* vn = vt_t + (size_t)(t6 + 1) * TILE_B;
            const int ob = bo ^ 32768;
            #pragma unroll
            for (int j = 0; j < 2; ++j) {
                const int off = j * 8192 + w * 1024;
                gload16(lds + ob + off,         kn + off + lane * 16);
                gload16(lds + ob + 16384 + off, vn + off + lane * 16);
            }
        }

        // ---- S^T = K Q^T : lane holds S[k=16t+4gq+r][q=lg] ----
        f32x4 sacc[4];
        #pragma unroll
        for (int t = 0; t < 4; ++t) sacc[t] = (f32x4){0.f, 0.f, 0.f, 0.f};
        __builtin_amdgcn_s_setprio(1);
        #pragma unroll
        for (int t = 0; t < 4; ++t) {
            const int rb = (t * 16 + lg) * 256;
            #pragma unroll
            for (int c = 0; c < 4; ++c) {
                const int byte = (rb + c * 64 + gq * 16) ^ sw;
                f16x8 kff = *(const f16x8*)(lds + bo + byte);
                sacc[t] = __builtin_amdgcn_mfma_f32_16x16x32_f16(kff, qf[c], sacc[t], 0, 0, 0);
            }
        }
        __builtin_amdgcn_s_setprio(0);

        // ---- online softmax with defer-max (row q = lg spread across gq) ----
        float tm = sacc[0][0];
        #pragma unroll
        for (int t = 0; t < 4; ++t)
            #pragma unroll
            for (int r = 0; r < 4; ++r) tm = fmaxf(tm, sacc[t][r]);
        tm = fmaxf(tm, __shfl_xor(tm, 16));
        tm = fmaxf(tm, __shfl_xor(tm, 32));
        const int grow = (tm > m_run + 8.f) ? 1 : 0;
        if (__any(grow)) {
            const float mn = fmaxf(m_run, tm);
            const float sc = __expf(m_run - mn);
            m_run = mn;
            l_run *= sc;
            float scq[4];
            #pragma unroll
            for (int r = 0; r < 4; ++r) scq[r] = __shfl(sc, gq * 4 + r);
            #pragma unroll
            for (int n = 0; n < 8; ++n) {
                oacc[n][0] *= scq[0]; oacc[n][1] *= scq[1];
                oacc[n][2] *= scq[2]; oacc[n][3] *= scq[3];
            }
        }
        float ps = 0.f;
        #pragma unroll
        for (int t = 0; t < 4; ++t)
            #pragma unroll
            for (int r = 0; r < 4; ++r) {
                float p = __expf(sacc[t][r] - m_run);
                sacc[t][r] = p;
                ps += p;
            }
        ps += __shfl_xor(ps, 16);
        ps += __shfl_xor(ps, 32);
        l_run += ps;

        // ---- pack P to f16 pairs; exchange to A-fragment layout in-register ----
        uint32_t dw[4][2];
        #pragma unroll
        for (int t = 0; t < 4; ++t) {
            dw[t][0] = pkf16(sacc[t][0], sacc[t][1]);
            dw[t][1] = pkf16(sacc[t][2], sacc[t][3]);
        }
        const int tclass = gq >> 1;
        const int sgl = (2 * (gq & 1)) * 16 + lg;
        #pragma unroll
        for (int kt = 0; kt < 2; ++kt) {
            uint32_t paw[4];
            #pragma unroll
            for (int wd = 0; wd < 4; ++wd) {
                const int src = sgl + (wd >> 1) * 16;
                uint32_t vA = (uint32_t)__shfl((int)dw[2 * kt][wd & 1], src);
                uint32_t vB = (uint32_t)__shfl((int)dw[2 * kt + 1][wd & 1], src);
                paw[wd] = tclass ? vB : vA;
            }
            union { uint32_t u[4]; f16x8 v; } pu;
            pu.u[0] = paw[0]; pu.u[1] = paw[1]; pu.u[2] = paw[2]; pu.u[3] = paw[3];
            f16x8 pa = pu.v;
            __builtin_amdgcn_s_setprio(1);
            #pragma unroll
            for (int n = 0; n < 8; ++n) {
                const int byte = ((n * 16 + lg) * 128 + kt * 64 + gq * 16) ^ sw;
                f16x8 vb = *(const f16x8*)(lds + bo + 16384 + byte);
                oacc[n] = __builtin_amdgcn_mfma_f32_16x16x32_f16(pa, vb, oacc[n], 0, 0, 0);
            }
            __builtin_amdgcn_s_setprio(0);
        }

        // drain prefetch + protect buffers (syncthreads implies full waitcnt)
        __syncthreads();
        bo ^= 32768;
    }

    // ---- epilogue ----
    const float inv_own = 1.f / l_run;
    float invq[4];
    #pragma unroll
    for (int r = 0; r < 4; ++r) invq[r] = __shfl(inv_own, gq * 4 + r);
    float* op = O + base + (size_t)qrow0 * D_DIM;
    #pragma unroll
    for (int n = 0; n < 8; ++n)
        #pragma unroll
        for (int r = 0; r < 4; ++r)
            op[(size_t)(gq * 4 + r) * D_DIM + n * 16 + lg] = oacc[n][r] * invq[r];
}

// ================= fallback (round-1 kernel, passes without ws) =================
#define PADK 136
#define PADV 72
#define LDS_SHORTS 31232

__global__ __launch_bounds__(256, 2)
void attn_fwd_fb(const float* __restrict__ Q, const float* __restrict__ K,
                 const float* __restrict__ V, float* __restrict__ O)
{
    __shared__ short lds[LDS_SHORTS];
    short* khi = lds;
    short* klo = lds + 8704;
    short* vt  = lds + 17408;
    short* pls = lds + 26624;

    const int tid  = threadIdx.x;
    const int w    = tid >> 6;
    const int lane = tid & 63;
    const int lg   = lane & 15;
    const int gq   = lane >> 4;
    const int qblk = blockIdx.x;
    const int bh   = blockIdx.y;
    const size_t base = (size_t)bh * S_LEN * D_DIM;
    const int qrow0 = qblk * 64 + w * 16;

    bf8_t qhi[4], qlo[4];
    {
        const float* qp = Q + base + (size_t)(qrow0 + lg) * D_DIM;
        #pragma unroll
        for (int c = 0; c < 4; ++c) {
            const int d0 = c * 32 + gq * 8;
            #pragma unroll
            for (int j = 0; j < 8; ++j) {
                float f = qp[d0 + j];
                short h = f2bf(f);
                qhi[c][j] = h;
                qlo[c][j] = f2bf(f - bf2f(h));
            }
        }
    }

    f32x4 oacc[8];
    #pragma unroll
    for (int n = 0; n < 8; ++n) oacc[n] = (f32x4){0.f, 0.f, 0.f, 0.f};
    float mrow[4] = {-INFINITY, -INFINITY, -INFINITY, -INFINITY};
    float lrow[4] = {0.f, 0.f, 0.f, 0.f};

    for (int kv = 0; kv < S_LEN; kv += 64) {
        __syncthreads();
        {
            const float4* kg = (const float4*)(K + base + (size_t)kv * D_DIM);
            const float4* vg = (const float4*)(V + base + (size_t)kv * D_DIM);
            #pragma unroll
            for (int it = 0; it < 8; ++it) {
                const int f4  = it * 256 + tid;
                const int row = f4 >> 5;
                const int d   = (f4 & 31) * 4;
                float4 kk = kg[f4];
                float4 vv = vg[f4];
                short h0 = f2bf(kk.x), h1 = f2bf(kk.y), h2 = f2bf(kk.z), h3 = f2bf(kk.w);
                short4 hw; hw.x = h0; hw.y = h1; hw.z = h2; hw.w = h3;
                *(short4*)(&khi[row * PADK + d]) = hw;
                short4 lw;
                lw.x = f2bf(kk.x - bf2f(h0));
                lw.y = f2bf(kk.y - bf2f(h1));
                lw.z = f2bf(kk.z - bf2f(h2));
                lw.w = f2bf(kk.w - bf2f(h3));
                *(short4*)(&klo[row * PADK + d]) = lw;
                vt[(d + 0) * PADV + row] = f2bf(vv.x);
                vt[(d + 1) * PADV + row] = f2bf(vv.y);
                vt[(d + 2) * PADV + row] = f2bf(vv.z);
                vt[(d + 3) * PADV + row] = f2bf(vv.w);
            }
        }
        __syncthreads();

        f32x4 sacc[4];
        #pragma unroll
        for (int t = 0; t < 4; ++t) sacc[t] = (f32x4){0.f, 0.f, 0.f, 0.f};
        #pragma unroll
        for (int t = 0; t < 4; ++t) {
            const int krow = t * 16 + lg;
            #pragma unroll
            for (int c = 0; c < 4; ++c) {
                bf8_t kh = *(const bf8_t*)(&khi[krow * PADK + c * 32 + gq * 8]);
                bf8_t kl = *(const bf8_t*)(&klo[krow * PADK + c * 32 + gq * 8]);
                sacc[t] = __builtin_amdgcn_mfma_f32_16x16x32_bf16(qhi[c], kh, sacc[t], 0, 0, 0);
                sacc[t] = __builtin_amdgcn_mfma_f32_16x16x32_bf16(qlo[c], kh, sacc[t], 0, 0, 0);
                sacc[t] = __builtin_amdgcn_mfma_f32_16x16x32_bf16(qhi[c], kl, sacc[t], 0, 0, 0);
            }
        }

        float scl[4];
        #pragma unroll
        for (int r = 0; r < 4; ++r) {
            float tm = fmaxf(fmaxf(sacc[0][r], sacc[1][r]),
                             fmaxf(sacc[2][r], sacc[3][r]));
            #pragma unroll
            for (int off = 8; off >= 1; off >>= 1)
                tm = fmaxf(tm, __shfl_xor(tm, off, 64));
            const float mn = fmaxf(mrow[r], tm);
            const float sc = __expf(mrow[r] - mn);
            float ps = 0.f;
            #pragma unroll
            for (int t = 0; t < 4; ++t) {
                float p = __expf(sacc[t][r] - mn);
                sacc[t][r] = p;
                ps += p;
            }
            #pragma unroll
            for (int off = 8; off >= 1; off >>= 1)
                ps += __shfl_xor(ps, off, 64);
            lrow[r] = lrow[r] * sc + ps;
            mrow[r] = mn;
            scl[r] = sc;
        }
        #pragma unroll
        for (int n = 0; n < 8; ++n) {
            oacc[n][0] *= scl[0];
            oacc[n][1] *= scl[1];
            oacc[n][2] *= scl[2];
            oacc[n][3] *= scl[3];
        }

        short* pw = pls + w * (16 * PADV);
        #pragma unroll
        for (int t = 0; t < 4; ++t)
            #pragma unroll
            for (int r = 0; r < 4; ++r)
                pw[(gq * 4 + r) * PADV + t * 16 + lg] = f2bf(sacc[t][r]);
        asm volatile("s_waitcnt lgkmcnt(0)" ::: "memory");

        #pragma unroll
        for (int kt = 0; kt < 2; ++kt) {
            bf8_t pa = *(const bf8_t*)(&pw[lg * PADV + kt * 32 + gq * 8]);
            #pragma unroll
            for (int n = 0; n < 8; ++n) {
                bf8_t vb = *(const bf8_t*)(&vt[(n * 16 + lg) * PADV + kt * 32 + gq * 8]);
                oacc[n] = __builtin_amdgcn_mfma_f32_16x16x32_bf16(pa, vb, oacc[n], 0, 0, 0);
            }
        }
    }

    float inv[4];
    #pragma unroll
    for (int r = 0; r < 4; ++r) inv[r] = 1.f / lrow[r];
    float* op = O + base + (size_t)qrow0 * D_DIM;
    #pragma unroll
    for (int n = 0; n < 8; ++n)
        #pragma unroll
        for (int r = 0; r < 4; ++r)
            op[(size_t)(gq * 4 + r) * D_DIM + n * 16 + lg] = oacc[n][r] * inv[r];
}

extern "C" void kernel_launch(void* const* d_in, const int* in_sizes, int n_in,
                              void* d_out, int out_size, void* d_ws, size_t ws_size,
                              hipStream_t stream) {
    const float* q = (const float*)d_in[0];
    const float* k = (const float*)d_in[1];
    const float* v = (const float*)d_in[2];
    float* o = (float*)d_out;
    if (ws_size >= (size_t)WS_NEED) {
        char* ws = (char*)d_ws;
        conv_kv<<<2048, 256, 0, stream>>>(k, v, ws, ws + WS_VT);
        attn_f16<<<1024, 512, 0, stream>>>(q, ws, o);
    } else {
        attn_fwd_fb<<<dim3(32, 64), 256, 0, stream>>>(q, k, v, o);
    }
}

// Round 6
// 221.948 us; speedup vs baseline: 3.9936x; 1.1488x over previous
//
#include <hip/hip_runtime.h>
#include <hip/hip_bf16.h>
#include <math.h>
#include <stdint.h>

#define S_LEN 2048
#define D_DIM 128

typedef _Float16 f16x8 __attribute__((ext_vector_type(8)));
typedef __fp16  fp16x2 __attribute__((ext_vector_type(2)));   // cvt_pkrtz return type
typedef short bf8_t __attribute__((ext_vector_type(8)));
typedef float f32x4 __attribute__((ext_vector_type(4)));
typedef float f32x16 __attribute__((ext_vector_type(16)));
typedef unsigned int uint32x2 __attribute__((ext_vector_type(2)));
typedef _Float16 f16_t;

__device__ __forceinline__ short f2bf(float f) {
    union { float f; unsigned u; } x; x.f = f;
    unsigned u = x.u;
    u += 0x7FFF + ((u >> 16) & 1);
    return (short)(u >> 16);
}
__device__ __forceinline__ float bf2f(short h) {
    union { unsigned u; float f; } x;
    x.u = ((unsigned)(unsigned short)h) << 16;
    return x.f;
}
__device__ __forceinline__ uint32_t pkf16(float a, float b) {
    union { fp16x2 h; uint32_t u; } x;
    x.h = __builtin_amdgcn_cvt_pkrtz(a, b);
    return x.u;
}
__device__ __forceinline__ uint32x2 plswap(uint32_t a, uint32_t b) {
    return __builtin_amdgcn_permlane32_swap(a, b, false, false);
}

#define TILE_B 16384
#define WS_VT  33554432u
#define WS_NEED 67108864u

typedef const uint32_t __attribute__((address_space(1))) ga_u32;
typedef uint32_t __attribute__((address_space(3))) la_u32;
__device__ __forceinline__ void gload16(void* l, const void* g) {
    __builtin_amdgcn_global_load_lds((ga_u32*)g, (la_u32*)l, 16, 0, 0);
}

// ---- phase 0: K -> f16 swizzled 64x128 tiles, V -> V^T f16 swizzled tiles ----
__global__ __launch_bounds__(256, 4)
void conv_kv(const float* __restrict__ K, const float* __restrict__ V,
             char* __restrict__ kf, char* __restrict__ vt)
{
    size_t tile = blockIdx.x;                       // bh*32 + s/64
    const float4* kg = (const float4*)(K + tile * (64 * 128));
    char* kd = kf + tile * TILE_B;
    #pragma unroll
    for (int it = 0; it < 8; ++it) {
        int idx = it * 256 + threadIdx.x;           // float4 index in tile
        int row = idx >> 5;
        int d0  = (idx & 31) * 4;
        float4 kk = kg[idx];
        uint32_t a = pkf16(kk.x, kk.y);
        uint32_t b = pkf16(kk.z, kk.w);
        uint32_t byte = (uint32_t)((row * 256 + d0 * 2) ^ ((row & 7) << 4));
        *(uint32_t*)(kd + byte)     = a;
        *(uint32_t*)(kd + byte + 4) = b;
    }
    const float* vs = V + tile * (64 * 128);
    char* vd = vt + tile * TILE_B;
    #pragma unroll
    for (int it = 0; it < 8; ++it) {
        int idx = it * 256 + threadIdx.x;
        int d  = idx & 127;
        int k0 = (idx >> 7) * 4;
        uint32_t a = pkf16(vs[(k0 + 0) * 128 + d], vs[(k0 + 1) * 128 + d]);
        uint32_t b = pkf16(vs[(k0 + 2) * 128 + d], vs[(k0 + 3) * 128 + d]);
        uint32_t byte = (uint32_t)((d * 128 + k0 * 2) ^ ((d & 7) << 4));
        *(uint32_t*)(vd + byte)     = a;
        *(uint32_t*)(vd + byte + 4) = b;
    }
}

// ---- main: flash attention f16, 32x32x16 MFMA, 4 waves x 32 q-rows ----
__global__ __launch_bounds__(256, 2)
void attn32(const float* __restrict__ Q, const char* __restrict__ ws,
            float* __restrict__ O)
{
    __shared__ __align__(16) char lds[65536];  // buf: [kf 16K | vt 16K] x2

    const int tid  = threadIdx.x;
    const int w    = tid >> 6;      // 0..3
    const int lane = tid & 63;
    const int ql   = lane & 31;     // q column in sacc; also k-row / d-row for frags
    const int h    = lane >> 5;     // half

    // chunked XCD swizzle: each XCD gets 128 consecutive new-ids = 8 heads
    const int fid  = blockIdx.x;               // 0..1023
    const int nid  = (fid & 7) * 128 + (fid >> 3);
    const int qblk = nid & 15;
    const int bh   = nid >> 4;

    const size_t base = (size_t)bh * S_LEN * D_DIM;
    const int qrow0 = qblk * 128 + w * 32;

    // Q f16 fragments (B-operand 32x32x16: n=q=ql, k(contraction d)=16c+8h+j)
    f16x8 qf[8];
    {
        const float* qp = Q + base + (size_t)(qrow0 + ql) * D_DIM;
        #pragma unroll
        for (int c = 0; c < 8; ++c) {
            const int d0 = c * 16 + h * 8;
            float4 f0 = *(const float4*)(qp + d0);
            float4 f1 = *(const float4*)(qp + d0 + 4);
            qf[c][0] = (f16_t)f0.x; qf[c][1] = (f16_t)f0.y;
            qf[c][2] = (f16_t)f0.z; qf[c][3] = (f16_t)f0.w;
            qf[c][4] = (f16_t)f1.x; qf[c][5] = (f16_t)f1.y;
            qf[c][6] = (f16_t)f1.z; qf[c][7] = (f16_t)f1.w;
        }
    }

    f32x16 oacc[4];
    #pragma unroll
    for (int nt = 0; nt < 4; ++nt)
        #pragma unroll
        for (int r = 0; r < 16; ++r) oacc[nt][r] = 0.f;
    float m_run = -INFINITY, l_run = 0.f;

    const char* kf_t = ws + (size_t)(bh * 32) * TILE_B;
    const char* vt_t = ws + WS_VT + (size_t)(bh * 32) * TILE_B;
    const int sw = (ql & 7) << 4;

    // prologue: stage tile 0 into buf0 (256 thr x 16B x 4 = 16KB per region)
    #pragma unroll
    for (int j = 0; j < 4; ++j) {
        const int off = j * 4096 + w * 1024;
        gload16(lds + off,         kf_t + off + lane * 16);
        gload16(lds + 16384 + off, vt_t + off + lane * 16);
    }
    __syncthreads();

    int bo = 0;
    for (int t6 = 0; t6 < 32; ++t6) {
        // ---- prefetch tile t6+1 into the other buffer ----
        if (t6 < 31) {
            const char* kn = kf_t + (size_t)(t6 + 1) * TILE_B;
            const char* vn = vt_t + (size_t)(t6 + 1) * TILE_B;
            const int ob = bo ^ 32768;
            #pragma unroll
            for (int j = 0; j < 4; ++j) {
                const int off = j * 4096 + w * 1024;
                gload16(lds + ob + off,         kn + off + lane * 16);
                gload16(lds + ob + 16384 + off, vn + off + lane * 16);
            }
        }

        // ---- S^T = K Q^T (two 32x32 tiles over k) ----
        f32x16 s0, s1;
        #pragma unroll
        for (int r = 0; r < 16; ++r) { s0[r] = 0.f; s1[r] = 0.f; }
        __builtin_amdgcn_s_setprio(1);
        #pragma unroll
        for (int c = 0; c < 8; ++c) {
            const int b0 = (ql * 256 + c * 32 + h * 16) ^ sw;
            f16x8 a0 = *(const f16x8*)(lds + bo + b0);
            f16x8 a1 = *(const f16x8*)(lds + bo + b0 + 8192);
            s0 = __builtin_amdgcn_mfma_f32_32x32x16_f16(a0, qf[c], s0, 0, 0, 0);
            s1 = __builtin_amdgcn_mfma_f32_32x32x16_f16(a1, qf[c], s1, 0, 0, 0);
        }
        __builtin_amdgcn_s_setprio(0);

        // ---- online softmax: row q=ql lives in lanes {l, l^32} only ----
        float tm = s0[0];
        #pragma unroll
        for (int r = 0; r < 16; ++r) { tm = fmaxf(tm, s0[r]); tm = fmaxf(tm, s1[r]); }
        {
            uint32x2 ts = plswap(__float_as_uint(tm), __float_as_uint(tm));
            tm = fmaxf(__uint_as_float(ts[0]), __uint_as_float(ts[1]));
        }
        if (__any(tm > m_run + 8.f)) {
            const float mn = fmaxf(m_run, tm);
            const float sc = __expf(m_run - mn);
            m_run = mn;
            l_run *= sc;
            #pragma unroll
            for (int r = 0; r < 16; ++r) {
                const float scq = __shfl(sc, (r & 3) + 8 * (r >> 2) + 4 * h);
                oacc[0][r] *= scq; oacc[1][r] *= scq;
                oacc[2][r] *= scq; oacc[3][r] *= scq;
            }
        }
        float ps = 0.f;
        #pragma unroll
        for (int r = 0; r < 16; ++r) {
            float p0 = __expf(s0[r] - m_run); s0[r] = p0; ps += p0;
            float p1 = __expf(s1[r] - m_run); s1[r] = p1; ps += p1;
        }
        {
            uint32x2 pss = plswap(__float_as_uint(ps), __float_as_uint(ps));
            ps = __uint_as_float(pss[0]) + __uint_as_float(pss[1]);
        }
        l_run += ps;

        // ---- pack P to f16, build A-frags via permlane32_swap (no LDS) ----
        f16x8 pf[4];
        {
            uint32_t pk[8];
            #pragma unroll
            for (int i = 0; i < 8; ++i) pk[i] = pkf16(s0[2 * i], s0[2 * i + 1]);
            uint32x2 r02 = plswap(pk[0], pk[2]), r13 = plswap(pk[1], pk[3]);
            uint32x2 r46 = plswap(pk[4], pk[6]), r57 = plswap(pk[5], pk[7]);
            union { uint32_t u[4]; f16x8 v; } b0, b1;
            b0.u[0] = r02[0]; b0.u[1] = r13[0]; b0.u[2] = r02[1]; b0.u[3] = r13[1];
            b1.u[0] = r46[0]; b1.u[1] = r57[0]; b1.u[2] = r46[1]; b1.u[3] = r57[1];
            pf[0] = b0.v; pf[1] = b1.v;
        }
        {
            uint32_t pk[8];
            #pragma unroll
            for (int i = 0; i < 8; ++i) pk[i] = pkf16(s1[2 * i], s1[2 * i + 1]);
            uint32x2 r02 = plswap(pk[0], pk[2]), r13 = plswap(pk[1], pk[3]);
            uint32x2 r46 = plswap(pk[4], pk[6]), r57 = plswap(pk[5], pk[7]);
            union { uint32_t u[4]; f16x8 v; } b0, b1;
            b0.u[0] = r02[0]; b0.u[1] = r13[0]; b0.u[2] = r02[1]; b0.u[3] = r13[1];
            b1.u[0] = r46[0]; b1.u[1] = r57[0]; b1.u[2] = r46[1]; b1.u[3] = r57[1];
            pf[2] = b0.v; pf[3] = b1.v;
        }

        // ---- O += P V  (A=P frags, B=V^T from LDS) ----
        __builtin_amdgcn_s_setprio(1);
        #pragma unroll
        for (int nt = 0; nt < 4; ++nt) {
            const int rb = (nt * 32 + ql) * 128;
            #pragma unroll
            for (int kc = 0; kc < 4; ++kc) {
                const int byte = (rb + kc * 32 + h * 16) ^ sw;
                f16x8 vb = *(const f16x8*)(lds + bo + 16384 + byte);
                oacc[nt] = __builtin_amdgcn_mfma_f32_32x32x16_f16(pf[kc], vb, oacc[nt], 0, 0, 0);
            }
        }
        __builtin_amdgcn_s_setprio(0);

        // drain prefetch + protect buffers (syncthreads implies full waitcnt)
        __syncthreads();
        bo ^= 32768;
    }

    // ---- epilogue: O[qrow0+qr][nt*32+ql], qr = (r&3)+8*(r>>2)+4h ----
    const float inv = 1.f / l_run;
    #pragma unroll
    for (int r = 0; r < 16; ++r) {
        const int qr = (r & 3) + 8 * (r >> 2) + 4 * h;
        const float iv = __shfl(inv, qr);
        float* op = O + base + (size_t)(qrow0 + qr) * D_DIM + ql;
        op[0]  = oacc[0][r] * iv;
        op[32] = oacc[1][r] * iv;
        op[64] = oacc[2][r] * iv;
        op[96] = oacc[3][r] * iv;
    }
}

// ================= fallback (round-1 kernel, passes without ws) =================
#define PADK 136
#define PADV 72
#define LDS_SHORTS 31232

__global__ __launch_bounds__(256, 2)
void attn_fwd_fb(const float* __restrict__ Q, const float* __restrict__ K,
                 const float* __restrict__ V, float* __restrict__ O)
{
    __shared__ short lds[LDS_SHORTS];
    short* khi = lds;
    short* klo = lds + 8704;
    short* vt  = lds + 17408;
    short* pls = lds + 26624;

    const int tid  = threadIdx.x;
    const int w    = tid >> 6;
    const int lane = tid & 63;
    const int lg   = lane & 15;
    const int gq   = lane >> 4;
    const int qblk = blockIdx.x;
    const int bh   = blockIdx.y;
    const size_t base = (size_t)bh * S_LEN * D_DIM;
    const int qrow0 = qblk * 64 + w * 16;

    bf8_t qhi[4], qlo[4];
    {
        const float* qp = Q + base + (size_t)(qrow0 + lg) * D_DIM;
        #pragma unroll
        for (int c = 0; c < 4; ++c) {
            const int d0 = c * 32 + gq * 8;
            #pragma unroll
            for (int j = 0; j < 8; ++j) {
                float f = qp[d0 + j];
                short hh = f2bf(f);
                qhi[c][j] = hh;
                qlo[c][j] = f2bf(f - bf2f(hh));
            }
        }
    }

    f32x4 oacc[8];
    #pragma unroll
    for (int n = 0; n < 8; ++n) oacc[n] = (f32x4){0.f, 0.f, 0.f, 0.f};
    float mrow[4] = {-INFINITY, -INFINITY, -INFINITY, -INFINITY};
    float lrow[4] = {0.f, 0.f, 0.f, 0.f};

    for (int kv = 0; kv < S_LEN; kv += 64) {
        __syncthreads();
        {
            const float4* kg = (const float4*)(K + base + (size_t)kv * D_DIM);
            const float4* vg = (const float4*)(V + base + (size_t)kv * D_DIM);
            #pragma unroll
            for (int it = 0; it < 8; ++it) {
                const int f4  = it * 256 + tid;
                const int row = f4 >> 5;
                const int d   = (f4 & 31) * 4;
                float4 kk = kg[f4];
                float4 vv = vg[f4];
                short h0 = f2bf(kk.x), h1 = f2bf(kk.y), h2 = f2bf(kk.z), h3 = f2bf(kk.w);
                short4 hw; hw.x = h0; hw.y = h1; hw.z = h2; hw.w = h3;
                *(short4*)(&khi[row * PADK + d]) = hw;
                short4 lw;
                lw.x = f2bf(kk.x - bf2f(h0));
                lw.y = f2bf(kk.y - bf2f(h1));
                lw.z = f2bf(kk.z - bf2f(h2));
                lw.w = f2bf(kk.w - bf2f(h3));
                *(short4*)(&klo[row * PADK + d]) = lw;
                vt[(d + 0) * PADV + row] = f2bf(vv.x);
                vt[(d + 1) * PADV + row] = f2bf(vv.y);
                vt[(d + 2) * PADV + row] = f2bf(vv.z);
                vt[(d + 3) * PADV + row] = f2bf(vv.w);
            }
        }
        __syncthreads();

        f32x4 sacc[4];
        #pragma unroll
        for (int t = 0; t < 4; ++t) sacc[t] = (f32x4){0.f, 0.f, 0.f, 0.f};
        #pragma unroll
        for (int t = 0; t < 4; ++t) {
            const int krow = t * 16 + lg;
            #pragma unroll
            for (int c = 0; c < 4; ++c) {
                bf8_t kh = *(const bf8_t*)(&khi[krow * PADK + c * 32 + gq * 8]);
                bf8_t kl = *(const bf8_t*)(&klo[krow * PADK + c * 32 + gq * 8]);
                sacc[t] = __builtin_amdgcn_mfma_f32_16x16x32_bf16(qhi[c], kh, sacc[t], 0, 0, 0);
                sacc[t] = __builtin_amdgcn_mfma_f32_16x16x32_bf16(qlo[c], kh, sacc[t], 0, 0, 0);
                sacc[t] = __builtin_amdgcn_mfma_f32_16x16x32_bf16(qhi[c], kl, sacc[t], 0, 0, 0);
            }
        }

        float scl[4];
        #pragma unroll
        for (int r = 0; r < 4; ++r) {
            float tm = fmaxf(fmaxf(sacc[0][r], sacc[1][r]),
                             fmaxf(sacc[2][r], sacc[3][r]));
            #pragma unroll
            for (int off = 8; off >= 1; off >>= 1)
                tm = fmaxf(tm, __shfl_xor(tm, off, 64));
            const float mn = fmaxf(mrow[r], tm);
            const float sc = __expf(mrow[r] - mn);
            float ps = 0.f;
            #pragma unroll
            for (int t = 0; t < 4; ++t) {
                float p = __expf(sacc[t][r] - mn);
                sacc[t][r] = p;
                ps += p;
            }
            #pragma unroll
            for (int off = 8; off >= 1; off >>= 1)
                ps += __shfl_xor(ps, off, 64);
            lrow[r] = lrow[r] * sc + ps;
            mrow[r] = mn;
            scl[r] = sc;
        }
        #pragma unroll
        for (int n = 0; n < 8; ++n) {
            oacc[n][0] *= scl[0];
            oacc[n][1] *= scl[1];
            oacc[n][2] *= scl[2];
            oacc[n][3] *= scl[3];
        }

        short* pw = pls + w * (16 * PADV);
        #pragma unroll
        for (int t = 0; t < 4; ++t)
            #pragma unroll
            for (int r = 0; r < 4; ++r)
                pw[(gq * 4 + r) * PADV + t * 16 + lg] = f2bf(sacc[t][r]);
        asm volatile("s_waitcnt lgkmcnt(0)" ::: "memory");

        #pragma unroll
        for (int kt = 0; kt < 2; ++kt) {
            bf8_t pa = *(const bf8_t*)(&pw[lg * PADV + kt * 32 + gq * 8]);
            #pragma unroll
            for (int n = 0; n < 8; ++n) {
                bf8_t vb = *(const bf8_t*)(&vt[(n * 16 + lg) * PADV + kt * 32 + gq * 8]);
                oacc[n] = __builtin_amdgcn_mfma_f32_16x16x32_bf16(pa, vb, oacc[n], 0, 0, 0);
            }
        }
    }

    float inv[4];
    #pragma unroll
    for (int r = 0; r < 4; ++r) inv[r] = 1.f / lrow[r];
    float* op = O + base + (size_t)qrow0 * D_DIM;
    #pragma unroll
    for (int n = 0; n < 8; ++n)
        #pragma unroll
        for (int r = 0; r < 4; ++r)
            op[(size_t)(gq * 4 + r) * D_DIM + n * 16 + lg] = oacc[n][r] * inv[r];
}

extern "C" void kernel_launch(void* const* d_in, const int* in_sizes, int n_in,
                              void* d_out, int out_size, void* d_ws, size_t ws_size,
                              hipStream_t stream) {
    const float* q = (const float*)d_in[0];
    const float* k = (const float*)d_in[1];
    const float* v = (const float*)d_in[2];
    float* o = (float*)d_out;
    if (ws_size >= (size_t)WS_NEED) {
        char* ws = (char*)d_ws;
        conv_kv<<<2048, 256, 0, stream>>>(k, v, ws, ws + WS_VT);
        attn32<<<1024, 256, 0, stream>>>(q, ws, o);
    } else {
        attn_fwd_fb<<<dim3(32, 64), 256, 0, stream>>>(q, k, v, o);
    }
}